// Round 1
// baseline (2964.905 us; speedup 1.0000x reference)
//
#include <hip/hip_runtime.h>

typedef unsigned short u16;
typedef __bf16 bf16_t;
typedef bf16_t bf16x8 __attribute__((ext_vector_type(8)));
typedef u16 u16x8 __attribute__((ext_vector_type(8)));
typedef float f32x4 __attribute__((ext_vector_type(4)));

#define BB 128
#define LL 256
#define DD 512
#define SS 512
#define DS 1024

__device__ __forceinline__ u16 f2bf(float f) {
  unsigned u = __float_as_uint(f);
  u += 0x7fffu + ((u >> 16) & 1u);
  return (u16)(u >> 16);
}

union FragU { u16x8 u; bf16x8 h; };

__device__ __forceinline__ bf16x8 cvt8(const float* __restrict__ p) {
  float4 a = *(const float4*)p;
  float4 b = *(const float4*)(p + 4);
  FragU r;
  r.u[0] = f2bf(a.x); r.u[1] = f2bf(a.y); r.u[2] = f2bf(a.z); r.u[3] = f2bf(a.w);
  r.u[4] = f2bf(b.x); r.u[5] = f2bf(b.y); r.u[6] = f2bf(b.z); r.u[7] = f2bf(b.w);
  return r.h;
}

__device__ __forceinline__ float sigmoidf_(float v) { return 1.f / (1.f + __expf(-v)); }

// One-time per launch: convert weights to bf16, zero state/h buffers, write outputs[:,0,:]=0.
__global__ void init_kernel(const float* __restrict__ w, const float* __restrict__ dw,
                            u16* __restrict__ wbf, u16* __restrict__ dwbf,
                            u16* __restrict__ hbuf, float* __restrict__ C,
                            float* __restrict__ CE, float* __restrict__ out) {
  const size_t NW = 3146752, NDW = 1024, NH = 131072, NC = 65536;
  const size_t total = NW + NDW + NH + NC + NC + 65536;
  for (size_t i = (size_t)blockIdx.x * blockDim.x + threadIdx.x; i < total;
       i += (size_t)gridDim.x * blockDim.x) {
    if (i < NW) wbf[i] = f2bf(w[i]);
    else if (i < NW + NDW) dwbf[i - NW] = f2bf(dw[i - NW]);
    else if (i < NW + NDW + NH) hbuf[i - NW - NDW] = 0;
    else if (i < NW + NDW + NH + NC) C[i - NW - NDW - NH] = 0.f;
    else if (i < NW + NDW + NH + 2 * NC) CE[i - NW - NDW - NH - NC] = 0.f;
    else { size_t j = i - (NW + NDW + NH + 2 * NC); out[(j >> 9) * 131072 + (j & 511)] = 0.f; }
  }
}

// One step of the scan. Grid = 256 WGs: bb = blockIdx>>6 (batch block of 32 rows),
// cg = blockIdx&63 (8 state cols -> 48 proj cols). 4 waves split K=1024 into quarters;
// partial accumulators reduced through LDS. Tile 3 carries the d_weight matvec in col 0.
__global__ __launch_bounds__(256) void step_kernel(
    const float* __restrict__ x, const float* __restrict__ td,
    const u16* __restrict__ wbf, const float* __restrict__ bias,
    const u16* __restrict__ dwbf, const float* __restrict__ dbias,
    const float* __restrict__ dbeta,
    const u16* __restrict__ hcur, u16* __restrict__ hnxt,
    float* __restrict__ C, float* __restrict__ CE,
    float* __restrict__ out, int t) {
  __shared__ float P[4][64][36];  // [kq][col][row+pad]; pad=4 keeps 16B align, ~2-way banks
  const int wg = blockIdx.x;
  const int bb = wg >> 6;
  const int cg = wg & 63;
  const int tid = threadIdx.x;
  const int kq = tid >> 6;   // wave id = K quarter
  const int l = tid & 63;
  const int l15 = l & 15;
  const int lk = l >> 4;

  // B (weight) row pointers: tile n covers local cols n*16..n*16+15, local col = gate*8 + j
  const u16* wp[3];
#pragma unroll
  for (int n = 0; n < 3; ++n) {
    int nl = n * 16 + l15;
    int prow = (nl >> 3) * SS + cg * 8 + (nl & 7);
    wp[n] = wbf + (size_t)prow * DS;
  }

  f32x4 acc[2][4] = {};
  const int k0 = kq * 256;
  const int rA0 = bb * 32 + l15;
  const int rA1 = rA0 + 16;

#pragma unroll
  for (int ks = 0; ks < 8; ++ks) {
    const int k = k0 + ks * 32 + lk * 8;
    bf16x8 a0, a1;
    if (k0 < 512) {  // x part of x_s (wave-uniform branch)
      a0 = cvt8(x + ((size_t)rA0 * LL + t) * DD + k);
      a1 = cvt8(x + ((size_t)rA1 * LL + t) * DD + k);
    } else {         // h part of x_s
      a0 = *(const bf16x8*)(hcur + (size_t)rA0 * SS + (k - 512));
      a1 = *(const bf16x8*)(hcur + (size_t)rA1 * SS + (k - 512));
    }
#pragma unroll
    for (int n = 0; n < 3; ++n) {
      bf16x8 b = *(const bf16x8*)(wp[n] + k);
      acc[0][n] = __builtin_amdgcn_mfma_f32_16x16x32_bf16(a0, b, acc[0][n], 0, 0, 0);
      acc[1][n] = __builtin_amdgcn_mfma_f32_16x16x32_bf16(a1, b, acc[1][n], 0, 0, 0);
    }
    FragU bd;
    if (l15 == 0) bd.h = *(const bf16x8*)(dwbf + k);
    else bd.u = (u16x8){0, 0, 0, 0, 0, 0, 0, 0};
    acc[0][3] = __builtin_amdgcn_mfma_f32_16x16x32_bf16(a0, bd.h, acc[0][3], 0, 0, 0);
    acc[1][3] = __builtin_amdgcn_mfma_f32_16x16x32_bf16(a1, bd.h, acc[1][3], 0, 0, 0);
  }

  // Spill partial sums: C/D layout col=lane&15, row=(lane>>4)*4+q -> contiguous f32x4 along row dim
#pragma unroll
  for (int m = 0; m < 2; ++m)
#pragma unroll
    for (int n = 0; n < 4; ++n)
      *(f32x4*)&P[kq][n * 16 + l15][m * 16 + lk * 4] = acc[m][n];
  __syncthreads();

  // Per-thread state update: thread owns (row r, state col j)
  const int r = tid >> 3;
  const int j = tid & 7;
  const int b = bb * 32 + r;
  const int s = cg * 8 + j;

  float pre[6];
#pragma unroll
  for (int g = 0; g < 6; ++g) {
    int col = g * 8 + j;
    pre[g] = P[0][col][r] + P[1][col][r] + P[2][col][r] + P[3][col][r] + bias[g * SS + s];
  }
  float dpre = P[0][48][r] + P[1][48][r] + P[2][48][r] + P[3][48][r] + dbias[0];

  float ig  = sigmoidf_(pre[0]);
  float fg  = sigmoidf_(pre[1]);
  float ieg = sigmoidf_(pre[2]);
  float feg = sigmoidf_(pre[3]);
  float z   = 2.f * sigmoidf_(pre[4]) - 1.f;
  float og  = sigmoidf_(pre[5]);

  float c  = C[(size_t)b * SS + s];   // c_t (precomputed by previous step)
  float ce = CE[(size_t)b * SS + s];  // ce_t
  float csn = fg * c + ig * z;        // cs_{t+1}
  float cen = feg * ce + ieg * z;     // ce_{t+1}
  float beta = dbeta[0];
  float v = beta * dpre;
  float sp = (v > 15.f) ? v : log1pf(__expf(v));
  float dn = sp / beta;               // d_{t+1}

  if (t < LL - 1) {
    float dt1 = td[(size_t)b * LL + (t + 1)];
    float cn = csn + (cen - csn) * __expf(-dn * dt1);  // c_{t+1}
    float hn = og * tanhf(cn);                          // h_{t+1}
    C[(size_t)b * SS + s] = cn;
    CE[(size_t)b * SS + s] = cen;
    hnxt[(size_t)b * SS + s] = f2bf(hn);
    out[((size_t)b * LL + (t + 1)) * SS + s] = hn;
  } else {
    // final_state = concat([o, cs, ce, d], axis=1), shape (1, 128, 1537)
    size_t fb = (size_t)16777216 + (size_t)b * 1537;
    out[fb + s] = og;
    out[fb + 512 + s] = csn;
    out[fb + 1024 + s] = cen;
    if (s == 0) out[fb + 1536] = dn;
  }
}

extern "C" void kernel_launch(void* const* d_in, const int* in_sizes, int n_in,
                              void* d_out, int out_size, void* d_ws, size_t ws_size,
                              hipStream_t stream) {
  const float* x     = (const float*)d_in[0];
  const float* td    = (const float*)d_in[1];
  const float* w     = (const float*)d_in[2];
  const float* bias  = (const float*)d_in[3];
  const float* dw    = (const float*)d_in[4];
  const float* dbias = (const float*)d_in[5];
  const float* dbeta = (const float*)d_in[6];
  float* out = (float*)d_out;

  char* ws = (char*)d_ws;
  u16* wbf   = (u16*)ws;                    // 3073*1024 bf16 = 6,293,504 B
  u16* dwbf  = (u16*)(ws + 6293504);        // 1024 bf16
  u16* hbuf  = (u16*)(ws + 6295552);        // 2 x 128x512 bf16 (double buffer)
  float* C   = (float*)(ws + 6557696);      // c_t, 128x512 f32
  float* CE  = (float*)(ws + 6819840);      // ce_t, 128x512 f32
  // total ws use: 7,081,984 B

  hipLaunchKernelGGL(init_kernel, dim3(2048), dim3(256), 0, stream,
                     w, dw, wbf, dwbf, hbuf, C, CE, out);
  for (int t = 0; t < 256; ++t) {
    const u16* hc = hbuf + (size_t)(t & 1) * 65536;
    u16* hn = hbuf + (size_t)((t + 1) & 1) * 65536;
    hipLaunchKernelGGL(step_kernel, dim3(256), dim3(256), 0, stream,
                       x, td, wbf, bias, dwbf, dbias, dbeta, hc, hn, C, CE, out, t);
  }
}